// Round 4
// baseline (5432.389 us; speedup 1.0000x reference)
//
#include <hip/hip_runtime.h>
#include <hip/hip_bf16.h>
#include <math.h>

using bf16 = __hip_bfloat16;
typedef __attribute__((ext_vector_type(8))) short s16x8;
typedef __attribute__((ext_vector_type(4))) float f32x4;
typedef __attribute__((ext_vector_type(8))) int i32x8;
typedef __attribute__((ext_vector_type(4))) int i32x4;

#define NEG_INF_F (-1e30f)

// ---------- constants ----------
static constexpr int BATCH = 16;
static constexpr int LC = 2048;
static constexpr int LQ = 512;
static constexpr int DIM = 512;
static constexpr int FEAT = 2048;          // 4*DIM
static constexpr int MC = BATCH * LC;      // 32768
static constexpr int MQ = BATCH * LQ;      // 8192

__device__ __forceinline__ float bfs2f(short s) {
    union { float f; unsigned u; } x;
    x.u = ((unsigned)(unsigned short)s) << 16;
    return x.f;
}
// OCP e4m3 byte -> float (epilogue decode)
__device__ __forceinline__ float fp8_to_f(unsigned b) {
    const unsigned s = b >> 7, e = (b >> 3) & 15, m = b & 7;
    const int ee = e ? (int)e : 1;
    const int mm = e ? (int)(8 + m) : (int)m;
    union { unsigned u; float f; } sc; sc.u = (unsigned)(ee + 117) << 23; // 2^(ee-10)
    const float v = (float)mm * sc.f;
    return s ? -v : v;
}
__device__ __forceinline__ unsigned char f2fp8(float v) {
    return (unsigned char)(__builtin_amdgcn_cvt_pk_fp8_f32(v, v, 0, false) & 0xff);
}
__device__ __forceinline__ uint2 pk8fp8(float a0, float a1, float a2, float a3,
                                        float a4, float a5, float a6, float a7) {
    uint2 r;
    int w0 = __builtin_amdgcn_cvt_pk_fp8_f32(a0, a1, 0, false);
    w0 = __builtin_amdgcn_cvt_pk_fp8_f32(a2, a3, w0, true);
    int w1 = __builtin_amdgcn_cvt_pk_fp8_f32(a4, a5, 0, false);
    w1 = __builtin_amdgcn_cvt_pk_fp8_f32(a6, a7, w1, true);
    r.x = (unsigned)w0; r.y = (unsigned)w1;
    return r;
}

#define GLL(gp, lp) __builtin_amdgcn_global_load_lds( \
    (const __attribute__((address_space(1))) void*)(gp), \
    (__attribute__((address_space(3))) void*)(lp), 16, 0, 0)

// ---------- fp32 -> fp8 e4m3, optional pre-scale ----------
__global__ __launch_bounds__(256) void cvt_f32_fp8(const float* __restrict__ in,
                                                   unsigned char* __restrict__ out,
                                                   int n, float scale) {
    int i = (blockIdx.x * 256 + threadIdx.x) * 4;
    if (i >= n) return;
    float4 v = *(const float4*)(in + i);
    int w0 = __builtin_amdgcn_cvt_pk_fp8_f32(v.x * scale, v.y * scale, 0, false);
    w0 = __builtin_amdgcn_cvt_pk_fp8_f32(v.z * scale, v.w * scale, w0, true);
    *(int*)(out + i) = w0;
}

// ---------- per-batch transpose: Q (B,LQ,DIM) f32 -> Qt8 (B,DIM,LQ) fp8 ----------
__global__ __launch_bounds__(256) void transpose_q_fp8(const float* __restrict__ Q,
                                                       unsigned char* __restrict__ Qt) {
    __shared__ float t[32][33];
    const int b = blockIdx.z;
    const int q0 = blockIdx.x * 32, d0 = blockIdx.y * 32;
    const int tx = threadIdx.x, ty = threadIdx.y; // 32 x 8
    const float* Qb = Q + (long)b * LQ * DIM;
    unsigned char* Qtb = Qt + (long)b * DIM * LQ;
#pragma unroll
    for (int i = 0; i < 32; i += 8)
        t[ty + i][tx] = Qb[(long)(q0 + ty + i) * DIM + d0 + tx];
    __syncthreads();
#pragma unroll
    for (int i = 0; i < 32; i += 8)
        Qtb[(long)(d0 + ty + i) * LQ + q0 + tx] = f2fp8(t[tx][ty + i]);
}

// ---------- generic MX-fp8 GEMM: Out[M,N] = (A fp8) @ (B fp8, pre-scaled 2^sB)^T ----------
// LDS rows 128 B, 16B chunks XOR-swizzled: chunk c of row m at c^(m&7).
enum { MODE_BF16 = 0, MODE_LRELU_FP8 = 1 };

template <int MODE, int SCALE_B>
__global__ __launch_bounds__(256, 3)
void gemm_fp8(const unsigned char* __restrict__ A8, const unsigned char* __restrict__ B8,
              void* __restrict__ Out, const float* __restrict__ bias,
              int N, int K,
              long strideA, long strideB, long strideO) {
    constexpr int BM = 128, BN = 128;
    __shared__ __align__(16) char As[BM * 128];
    __shared__ __align__(16) char Bs[BN * 128];

    const int z = blockIdx.z;
    const unsigned char* Ab = A8 + (long)z * strideA;
    const unsigned char* Bb = B8 + (long)z * strideB;

    const int tid = threadIdx.x;
    const int wave = tid >> 6, lane = tid & 63;
    const int wm = (wave >> 1) * 64, wn = (wave & 1) * 64;
    const int lrow = lane & 15, lq = lane >> 4;

    const int bm0 = blockIdx.y * BM;
    const int bn0 = blockIdx.x * BN;

    const int p = tid & 7, r0 = tid >> 3;
    const int xo = (p ^ (r0 & 7)) * 16;
    const unsigned char* agp = Ab + (long)(bm0 + r0) * K + xo;
    const unsigned char* bgp = Bb + (long)(bn0 + r0) * K + xo;
    char* asl = As + tid * 16;
    char* bsl = Bs + tid * 16;
    const long rowskip = (long)32 * K;

    int offA0[4], offA1[4], offB0[4], offB1[4];
#pragma unroll
    for (int f = 0; f < 4; f++) {
        const int ra = wm + f * 16 + lrow;
        offA0[f] = ra * 128 + (((lq * 2 + 0) ^ (ra & 7)) * 16);
        offA1[f] = ra * 128 + (((lq * 2 + 1) ^ (ra & 7)) * 16);
        const int rb = wn + f * 16 + lrow;
        offB0[f] = rb * 128 + (((lq * 2 + 0) ^ (rb & 7)) * 16);
        offB1[f] = rb * 128 + (((lq * 2 + 1) ^ (rb & 7)) * 16);
    }

    f32x4 acc[4][4];
#pragma unroll
    for (int i = 0; i < 4; i++)
#pragma unroll
        for (int j = 0; j < 4; j++) acc[i][j] = (f32x4){0.f, 0.f, 0.f, 0.f};

    for (int k0 = 0; k0 < K; k0 += 128) {
#pragma unroll
        for (int r = 0; r < 4; r++) {
            GLL(agp + (long)r * rowskip, asl + r * 4096);
            GLL(bgp + (long)r * rowskip, bsl + r * 4096);
        }
        agp += 128; bgp += 128;
        __syncthreads();

        i32x8 af[4];
#pragma unroll
        for (int f = 0; f < 4; f++) {
            const i32x4 lo = *(const i32x4*)(As + offA0[f]);
            const i32x4 hi = *(const i32x4*)(As + offA1[f]);
            af[f][0] = lo[0]; af[f][1] = lo[1]; af[f][2] = lo[2]; af[f][3] = lo[3];
            af[f][4] = hi[0]; af[f][5] = hi[1]; af[f][6] = hi[2]; af[f][7] = hi[3];
        }
#pragma unroll
        for (int j = 0; j < 4; j++) {
            i32x8 bj;
            {
                const i32x4 lo = *(const i32x4*)(Bs + offB0[j]);
                const i32x4 hi = *(const i32x4*)(Bs + offB1[j]);
                bj[0] = lo[0]; bj[1] = lo[1]; bj[2] = lo[2]; bj[3] = lo[3];
                bj[4] = hi[0]; bj[5] = hi[1]; bj[6] = hi[2]; bj[7] = hi[3];
            }
#pragma unroll
            for (int i = 0; i < 4; i++)
                acc[i][j] = __builtin_amdgcn_mfma_scale_f32_16x16x128_f8f6f4(
                    af[i], bj, acc[i][j], 0, 0, 0, 127, 0, SCALE_B);
        }
        __syncthreads();
    }

    // epilogue: C/D layout col=lane&15, row=(lane>>4)*4+reg
#pragma unroll
    for (int j = 0; j < 4; j++) {
        const int n = bn0 + wn + j * 16 + lrow;
        const float bn_bias = (MODE == MODE_LRELU_FP8) ? bias[n] : 0.f;
#pragma unroll
        for (int i = 0; i < 4; i++) {
#pragma unroll
            for (int r = 0; r < 4; r++) {
                const int m = bm0 + wm + i * 16 + lq * 4 + r;
                const long off = (long)z * strideO + (long)m * N + n;
                float v = acc[i][j][r];
                if (MODE == MODE_LRELU_FP8) {
                    v += bn_bias;
                    v = v > 0.f ? v : 0.01f * v;
                    ((unsigned char*)Out)[off] = f2fp8(v);
                } else {
                    ((bf16*)Out)[off] = __float2bfloat16(v);
                }
            }
        }
    }
}

// ---------- fused dual GEMM, MX-fp8, BM=128 BN=64 for 3 blocks/CU ----------
__global__ __launch_bounds__(256, 3)
void gemm_dual_fp8(const unsigned char* __restrict__ A8,
                   const unsigned char* __restrict__ Bf8,
                   const unsigned char* __restrict__ Bg8,
                   float* __restrict__ Out,
                   const float* __restrict__ biasf, const float* __restrict__ biasg,
                   const unsigned char* __restrict__ cat8,
                   const int* __restrict__ cmask) {
    constexpr int BM = 128, BN = 64;
    constexpr int N = FEAT, K = FEAT;
    __shared__ __align__(16) char As[BM * 128];   // 16 KB
    __shared__ __align__(16) char Bfs[BN * 128];  // 8 KB
    __shared__ __align__(16) char Bgs[BN * 128];  // 8 KB

    const int tid = threadIdx.x;
    const int wave = tid >> 6, lane = tid & 63;
    const int wm = (wave >> 1) * 64, wn = (wave & 1) * 32;
    const int lrow = lane & 15, lq = lane >> 4;

    const int bm0 = blockIdx.y * BM;
    const int bn0 = blockIdx.x * BN;

    const int p = tid & 7, r0 = tid >> 3;
    const int xo = (p ^ (r0 & 7)) * 16;
    const unsigned char* agp = A8 + (long)(bm0 + r0) * K + xo;
    const unsigned char* bfgp = Bf8 + (long)(bn0 + r0) * K + xo;
    const unsigned char* bggp = Bg8 + (long)(bn0 + r0) * K + xo;
    char* asl = As + tid * 16;
    char* bfl = Bfs + tid * 16;
    char* bgl = Bgs + tid * 16;
    const long rowskip = (long)32 * K;

    int offA0[4], offA1[4], offB0[2], offB1[2];
#pragma unroll
    for (int f = 0; f < 4; f++) {
        const int ra = wm + f * 16 + lrow;
        offA0[f] = ra * 128 + (((lq * 2 + 0) ^ (ra & 7)) * 16);
        offA1[f] = ra * 128 + (((lq * 2 + 1) ^ (ra & 7)) * 16);
    }
#pragma unroll
    for (int f = 0; f < 2; f++) {
        const int rb = wn + f * 16 + lrow;
        offB0[f] = rb * 128 + (((lq * 2 + 0) ^ (rb & 7)) * 16);
        offB1[f] = rb * 128 + (((lq * 2 + 1) ^ (rb & 7)) * 16);
    }

    f32x4 accf[4][2], accg[4][2];
#pragma unroll
    for (int i = 0; i < 4; i++)
#pragma unroll
        for (int j = 0; j < 2; j++) {
            accf[i][j] = (f32x4){0.f, 0.f, 0.f, 0.f};
            accg[i][j] = (f32x4){0.f, 0.f, 0.f, 0.f};
        }

    for (int k0 = 0; k0 < K; k0 += 128) {
#pragma unroll
        for (int r = 0; r < 4; r++)
            GLL(agp + (long)r * rowskip, asl + r * 4096);
#pragma unroll
        for (int r = 0; r < 2; r++) {
            GLL(bfgp + (long)r * rowskip, bfl + r * 4096);
            GLL(bggp + (long)r * rowskip, bgl + r * 4096);
        }
        agp += 128; bfgp += 128; bggp += 128;
        __syncthreads();

        i32x8 af[4];
#pragma unroll
        for (int f = 0; f < 4; f++) {
            const i32x4 lo = *(const i32x4*)(As + offA0[f]);
            const i32x4 hi = *(const i32x4*)(As + offA1[f]);
            af[f][0] = lo[0]; af[f][1] = lo[1]; af[f][2] = lo[2]; af[f][3] = lo[3];
            af[f][4] = hi[0]; af[f][5] = hi[1]; af[f][6] = hi[2]; af[f][7] = hi[3];
        }
#pragma unroll
        for (int j = 0; j < 2; j++) {
            i32x8 bfj, bgj;
            {
                const i32x4 lo = *(const i32x4*)(Bfs + offB0[j]);
                const i32x4 hi = *(const i32x4*)(Bfs + offB1[j]);
                bfj[0] = lo[0]; bfj[1] = lo[1]; bfj[2] = lo[2]; bfj[3] = lo[3];
                bfj[4] = hi[0]; bfj[5] = hi[1]; bfj[6] = hi[2]; bfj[7] = hi[3];
            }
            {
                const i32x4 lo = *(const i32x4*)(Bgs + offB0[j]);
                const i32x4 hi = *(const i32x4*)(Bgs + offB1[j]);
                bgj[0] = lo[0]; bgj[1] = lo[1]; bgj[2] = lo[2]; bgj[3] = lo[3];
                bgj[4] = hi[0]; bgj[5] = hi[1]; bgj[6] = hi[2]; bgj[7] = hi[3];
            }
#pragma unroll
            for (int i = 0; i < 4; i++)
                accf[i][j] = __builtin_amdgcn_mfma_scale_f32_16x16x128_f8f6f4(
                    af[i], bfj, accf[i][j], 0, 0, 0, 127, 0, 122);
#pragma unroll
            for (int i = 0; i < 4; i++)
                accg[i][j] = __builtin_amdgcn_mfma_scale_f32_16x16x128_f8f6f4(
                    af[i], bgj, accg[i][j], 0, 0, 0, 127, 0, 122);
        }
        __syncthreads();
    }

#pragma unroll
    for (int j = 0; j < 2; j++) {
        const int n = bn0 + wn + j * 16 + lrow;
        const float bfb = biasf[n];
        const float bgb = biasg[n];
#pragma unroll
        for (int i = 0; i < 4; i++) {
#pragma unroll
            for (int r = 0; r < 4; r++) {
                const int m = bm0 + wm + i * 16 + lq * 4 + r;
                const long off = (long)m * N + n;
                const float vf = accf[i][j][r] + bfb;
                const float vg = accg[i][j][r] + bgb;
                const float e = __expf(2.0f * fabsf(vf));
                const float th = copysignf(1.0f - 2.0f / (e + 1.0f), vf);
                const float g = 1.0f / (1.0f + __expf(-vg));
                const float c = fp8_to_f(cat8[off]);
                Out[off] = cmask[m] ? (g * th + (1.0f - g) * c) : NEG_INF_F;
            }
        }
    }
}

// ---------- masked row softmax: S bf16 in, S_ fp8 out ----------
__global__ __launch_bounds__(256) void softmax_rows(const bf16* __restrict__ S,
                                                    unsigned char* __restrict__ S8,
                                                    const int* __restrict__ Cmask,
                                                    const int* __restrict__ Qmask) {
    const int row = blockIdx.x;         // 0 .. MC-1
    const int b = row >> 11;            // LC = 2048
    const int tid = threadIdx.x;
    const bf16* srow = S + (long)row * LQ;
    unsigned char* orow = S8 + (long)row * LQ;
    const int* qm = Qmask + b * LQ;
    __shared__ float red[8];

    if (Cmask[row] == 0) {
        // ref: uniform 1/512 = 2^-9 = e4m3 byte 0x01 exactly
        orow[tid] = 0x01; orow[tid + 256] = 0x01;
        return;
    }
    const int q0 = qm[tid], q1 = qm[tid + 256];
    float v0 = q0 ? __bfloat162float(srow[tid]) : -3e38f;
    float v1 = q1 ? __bfloat162float(srow[tid + 256]) : -3e38f;
    float mx = fmaxf(v0, v1);
#pragma unroll
    for (int o = 32; o > 0; o >>= 1) mx = fmaxf(mx, __shfl_down(mx, o, 64));
    const int wave = tid >> 6, lane = tid & 63;
    if (lane == 0) red[wave] = mx;
    __syncthreads();
    const float m4 = fmaxf(fmaxf(red[0], red[1]), fmaxf(red[2], red[3]));
    float e0 = q0 ? __expf(v0 - m4) : 0.f;
    float e1 = q1 ? __expf(v1 - m4) : 0.f;
    float s = e0 + e1;
#pragma unroll
    for (int o = 32; o > 0; o >>= 1) s += __shfl_down(s, o, 64);
    if (lane == 0) red[4 + wave] = s;
    __syncthreads();
    const float tot = red[4] + red[5] + red[6] + red[7];
    if (!(tot > 0.f)) {
        orow[tid] = 0x01; orow[tid + 256] = 0x01;
        return;
    }
    const float inv = 1.0f / tot;
    orow[tid] = f2fp8(e0 * inv);
    orow[tid + 256] = f2fp8(e1 * inv);
}

// ---------- build cat = [C | attn | attn-C | attn*C] fp8, from f32 C + bf16 attn ----------
__global__ __launch_bounds__(256) void build_cat(const float* __restrict__ C,
                                                 const bf16* __restrict__ attn,
                                                 unsigned char* __restrict__ cat8) {
    const long t = (long)blockIdx.x * 256 + threadIdx.x;
    const int m = (int)(t >> 6);
    const int c = (int)(t & 63) << 3;
    const float4 c0 = *(const float4*)(C + (long)m * DIM + c);
    const float4 c1 = *(const float4*)(C + (long)m * DIM + c + 4);
    const s16x8 av = *(const s16x8*)((const short*)attn + (long)m * DIM + c);
    float cf[8] = {c0.x, c0.y, c0.z, c0.w, c1.x, c1.y, c1.z, c1.w};
    float af_[8];
#pragma unroll
    for (int i = 0; i < 8; i++) af_[i] = bfs2f(av[i]);
    unsigned char* rowp = cat8 + (long)m * FEAT + c;
    *(uint2*)(rowp) = pk8fp8(cf[0], cf[1], cf[2], cf[3], cf[4], cf[5], cf[6], cf[7]);
    *(uint2*)(rowp + 512) = pk8fp8(af_[0], af_[1], af_[2], af_[3], af_[4], af_[5], af_[6], af_[7]);
    *(uint2*)(rowp + 1024) = pk8fp8(af_[0] - cf[0], af_[1] - cf[1], af_[2] - cf[2], af_[3] - cf[3],
                                    af_[4] - cf[4], af_[5] - cf[5], af_[6] - cf[6], af_[7] - cf[7]);
    *(uint2*)(rowp + 1536) = pk8fp8(af_[0] * cf[0], af_[1] * cf[1], af_[2] * cf[2], af_[3] * cf[3],
                                    af_[4] * cf[4], af_[5] * cf[5], af_[6] * cf[6], af_[7] * cf[7]);
}

extern "C" void kernel_launch(void* const* d_in, const int* in_sizes, int n_in,
                              void* d_out, int out_size, void* d_ws, size_t ws_size,
                              hipStream_t stream) {
    (void)in_sizes; (void)n_in; (void)out_size; (void)ws_size;
    const float* C = (const float*)d_in[0];
    const float* Q = (const float*)d_in[1];
    const int* Cmask = (const int*)d_in[2];
    const int* Qmask = (const int*)d_in[3];
    const float* W1 = (const float*)d_in[4];
    const float* b1 = (const float*)d_in[5];
    const float* Wf = (const float*)d_in[6];
    const float* bfp = (const float*)d_in[7];
    const float* Wg = (const float*)d_in[8];
    const float* bgp = (const float*)d_in[9];
    float* out = (float*)d_out;

    // ---- workspace layout. Everything below 134,217,728 is dead before
    // build_cat writes cat8 (first 67 MB); attn/Wf8/Wg8 live above. ----
    char* ws = (char*)d_ws;
    unsigned char* cat8 = (unsigned char*)(ws + 0);          //  67,108,864
    unsigned char* C8   = (unsigned char*)(ws + 0);          //  16,777,216 (dead after lrelu-C)
    unsigned char* Q8   = (unsigned char*)(ws + 16777216);   //   4,194,304 (dead after lrelu-Q)
    unsigned char* Qt8  = (unsigned char*)(ws + 20971520);   //   4,194,304 (dead after attn)
    unsigned char* C_8  = (unsigned char*)(ws + 25165824);   //  16,777,216 (dead after S)
    unsigned char* Q_8  = (unsigned char*)(ws + 41943040);   //   4,194,304 (dead after S)
    bf16*          S    = (bf16*)(ws + 46137344);            //  33,554,432 (dead after softmax)
    unsigned char* S_8  = (unsigned char*)(ws + 79691776);   //  16,777,216 (dead after attn)
    unsigned char* W1_8 = (unsigned char*)(ws + 96468992);   //     262,144
    bf16*          attn = (bf16*)(ws + 134217728);           //  33,554,432
    unsigned char* Wf8  = (unsigned char*)(ws + 167772160);  //   4,194,304
    unsigned char* Wg8  = (unsigned char*)(ws + 171966464);  //   4,194,304 (end ~176 MB)

    // 1. conversions: activations scale 1, weights pre-scaled x32 (MX scale 2^-5)
    cvt_f32_fp8<<<16384, 256, 0, stream>>>(C, C8, MC * DIM, 1.0f);
    cvt_f32_fp8<<<4096, 256, 0, stream>>>(Q, Q8, MQ * DIM, 1.0f);
    cvt_f32_fp8<<<256, 256, 0, stream>>>(W1, W1_8, DIM * DIM, 32.0f);
    cvt_f32_fp8<<<4096, 256, 0, stream>>>(Wf, Wf8, FEAT * FEAT, 32.0f);
    cvt_f32_fp8<<<4096, 256, 0, stream>>>(Wg, Wg8, FEAT * FEAT, 32.0f);
    transpose_q_fp8<<<dim3(16, 16, 16), dim3(32, 8), 0, stream>>>(Q, Qt8);

    // 2. C_ = lrelu(C@W1^T + b1) fp8 ; Q_ likewise (B-scale 2^-5 = byte 122)
    gemm_fp8<MODE_LRELU_FP8, 122><<<dim3(4, 256, 1), 256, 0, stream>>>(
        C8, W1_8, C_8, b1, DIM, DIM, 0, 0, 0);
    gemm_fp8<MODE_LRELU_FP8, 122><<<dim3(4, 64, 1), 256, 0, stream>>>(
        Q8, W1_8, Q_8, b1, DIM, DIM, 0, 0, 0);

    // 3. S[b] = C_[b] @ Q_[b]^T  (bf16 logits; both operands scale 1 = byte 127)
    gemm_fp8<MODE_BF16, 127><<<dim3(4, 16, 16), 256, 0, stream>>>(
        C_8, Q_8, S, nullptr, LQ, DIM,
        (long)LC * DIM, (long)LQ * DIM, (long)LC * LQ);

    // 4. masked softmax -> S_ fp8
    softmax_rows<<<MC, 256, 0, stream>>>(S, S_8, Cmask, Qmask);

    // 5. attn[b] = S_[b] @ Q[b]  (B = Qt8)  -> bf16
    gemm_fp8<MODE_BF16, 127><<<dim3(4, 16, 16), 256, 0, stream>>>(
        S_8, Qt8, attn, nullptr, DIM, LQ,
        (long)LC * LQ, (long)DIM * LQ, (long)LC * DIM);

    // 6. cat8 = [C | attn | attn-C | attn*C] (fp8, from f32 C)
    build_cat<<<8192, 256, 0, stream>>>(C, attn, cat8);

    // 7+8 fused dual MX-fp8 GEMM + activations + gate blend + Cmask (fp32 out)
    gemm_dual_fp8<<<dim3(32, 256, 1), 256, 0, stream>>>(
        cat8, Wf8, Wg8, out, bfp, bgp, cat8, Cmask);
}

// Round 5
// 962.394 us; speedup vs baseline: 5.6447x; 5.6447x over previous
//
#include <hip/hip_runtime.h>
#include <hip/hip_bf16.h>
#include <math.h>

using bf16 = __hip_bfloat16;
typedef __attribute__((ext_vector_type(8))) short s16x8;
typedef __attribute__((ext_vector_type(4))) float f32x4;
typedef __attribute__((ext_vector_type(8))) int i32x8;
typedef __attribute__((ext_vector_type(4))) int i32x4;

#define NEG_INF_F (-1e30f)

// ---------- constants ----------
static constexpr int BATCH = 16;
static constexpr int LC = 2048;
static constexpr int LQ = 512;
static constexpr int DIM = 512;
static constexpr int FEAT = 2048;          // 4*DIM
static constexpr int MC = BATCH * LC;      // 32768
static constexpr int MQ = BATCH * LQ;      // 8192

__device__ __forceinline__ float bfs2f(short s) {
    union { float f; unsigned u; } x;
    x.u = ((unsigned)(unsigned short)s) << 16;
    return x.f;
}
// OCP e4m3 byte -> float (epilogue decode)
__device__ __forceinline__ float fp8_to_f(unsigned b) {
    const unsigned s = b >> 7, e = (b >> 3) & 15, m = b & 7;
    const int ee = e ? (int)e : 1;
    const int mm = e ? (int)(8 + m) : (int)m;
    union { unsigned u; float f; } sc; sc.u = (unsigned)(ee + 117) << 23; // 2^(ee-10)
    const float v = (float)mm * sc.f;
    return s ? -v : v;
}
__device__ __forceinline__ unsigned char f2fp8(float v) {
    return (unsigned char)(__builtin_amdgcn_cvt_pk_fp8_f32(v, v, 0, false) & 0xff);
}
__device__ __forceinline__ uint2 pk8fp8(float a0, float a1, float a2, float a3,
                                        float a4, float a5, float a6, float a7) {
    uint2 r;
    int w0 = __builtin_amdgcn_cvt_pk_fp8_f32(a0, a1, 0, false);
    w0 = __builtin_amdgcn_cvt_pk_fp8_f32(a2, a3, w0, true);
    int w1 = __builtin_amdgcn_cvt_pk_fp8_f32(a4, a5, 0, false);
    w1 = __builtin_amdgcn_cvt_pk_fp8_f32(a6, a7, w1, true);
    r.x = (unsigned)w0; r.y = (unsigned)w1;
    return r;
}

#define GLL(gp, lp) __builtin_amdgcn_global_load_lds( \
    (const __attribute__((address_space(1))) void*)(gp), \
    (__attribute__((address_space(3))) void*)(lp), 16, 0, 0)

// ---------- fp32 -> fp8 e4m3, optional pre-scale ----------
__global__ __launch_bounds__(256) void cvt_f32_fp8(const float* __restrict__ in,
                                                   unsigned char* __restrict__ out,
                                                   int n, float scale) {
    int i = (blockIdx.x * 256 + threadIdx.x) * 4;
    if (i >= n) return;
    float4 v = *(const float4*)(in + i);
    int w0 = __builtin_amdgcn_cvt_pk_fp8_f32(v.x * scale, v.y * scale, 0, false);
    w0 = __builtin_amdgcn_cvt_pk_fp8_f32(v.z * scale, v.w * scale, w0, true);
    *(int*)(out + i) = w0;
}

// ---------- per-batch transpose: Q (B,LQ,DIM) f32 -> Qt8 (B,DIM,LQ) fp8 ----------
__global__ __launch_bounds__(256) void transpose_q_fp8(const float* __restrict__ Q,
                                                       unsigned char* __restrict__ Qt) {
    __shared__ float t[32][33];
    const int b = blockIdx.z;
    const int q0 = blockIdx.x * 32, d0 = blockIdx.y * 32;
    const int tx = threadIdx.x, ty = threadIdx.y; // 32 x 8
    const float* Qb = Q + (long)b * LQ * DIM;
    unsigned char* Qtb = Qt + (long)b * DIM * LQ;
#pragma unroll
    for (int i = 0; i < 32; i += 8)
        t[ty + i][tx] = Qb[(long)(q0 + ty + i) * DIM + d0 + tx];
    __syncthreads();
#pragma unroll
    for (int i = 0; i < 32; i += 8)
        Qtb[(long)(d0 + ty + i) * LQ + q0 + tx] = f2fp8(t[tx][ty + i]);
}

// ---------- generic MX-fp8 GEMM: Out[M,N] = (A fp8) @ (B fp8, pre-scaled 2^sB)^T ----------
// LDS rows 128 B, 16B chunks XOR-swizzled: chunk c of row m at c^(m&7).
enum { MODE_BF16 = 0, MODE_LRELU_FP8 = 1 };

template <int MODE, int SCALE_B>
__global__ __launch_bounds__(256, 3)
void gemm_fp8(const unsigned char* __restrict__ A8, const unsigned char* __restrict__ B8,
              void* __restrict__ Out, const float* __restrict__ bias,
              int N, int K,
              long strideA, long strideB, long strideO) {
    constexpr int BM = 128, BN = 128;
    __shared__ __align__(16) char As[BM * 128];
    __shared__ __align__(16) char Bs[BN * 128];

    const int z = blockIdx.z;
    const unsigned char* Ab = A8 + (long)z * strideA;
    const unsigned char* Bb = B8 + (long)z * strideB;

    const int tid = threadIdx.x;
    const int wave = tid >> 6, lane = tid & 63;
    const int wm = (wave >> 1) * 64, wn = (wave & 1) * 64;
    const int lrow = lane & 15, lq = lane >> 4;

    const int bm0 = blockIdx.y * BM;
    const int bn0 = blockIdx.x * BN;

    const int p = tid & 7, r0 = tid >> 3;
    const int xo = (p ^ (r0 & 7)) * 16;
    const unsigned char* agp = Ab + (long)(bm0 + r0) * K + xo;
    const unsigned char* bgp = Bb + (long)(bn0 + r0) * K + xo;
    char* asl = As + tid * 16;
    char* bsl = Bs + tid * 16;
    const long rowskip = (long)32 * K;

    int offA0[4], offA1[4], offB0[4], offB1[4];
#pragma unroll
    for (int f = 0; f < 4; f++) {
        const int ra = wm + f * 16 + lrow;
        offA0[f] = ra * 128 + (((lq * 2 + 0) ^ (ra & 7)) * 16);
        offA1[f] = ra * 128 + (((lq * 2 + 1) ^ (ra & 7)) * 16);
        const int rb = wn + f * 16 + lrow;
        offB0[f] = rb * 128 + (((lq * 2 + 0) ^ (rb & 7)) * 16);
        offB1[f] = rb * 128 + (((lq * 2 + 1) ^ (rb & 7)) * 16);
    }

    f32x4 acc[4][4];
#pragma unroll
    for (int i = 0; i < 4; i++)
#pragma unroll
        for (int j = 0; j < 4; j++) acc[i][j] = (f32x4){0.f, 0.f, 0.f, 0.f};

    for (int k0 = 0; k0 < K; k0 += 128) {
#pragma unroll
        for (int r = 0; r < 4; r++) {
            GLL(agp + (long)r * rowskip, asl + r * 4096);
            GLL(bgp + (long)r * rowskip, bsl + r * 4096);
        }
        agp += 128; bgp += 128;
        __syncthreads();

        i32x8 af[4];
#pragma unroll
        for (int f = 0; f < 4; f++) {
            const i32x4 lo = *(const i32x4*)(As + offA0[f]);
            const i32x4 hi = *(const i32x4*)(As + offA1[f]);
            af[f][0] = lo[0]; af[f][1] = lo[1]; af[f][2] = lo[2]; af[f][3] = lo[3];
            af[f][4] = hi[0]; af[f][5] = hi[1]; af[f][6] = hi[2]; af[f][7] = hi[3];
        }
#pragma unroll
        for (int j = 0; j < 4; j++) {
            i32x8 bj;
            {
                const i32x4 lo = *(const i32x4*)(Bs + offB0[j]);
                const i32x4 hi = *(const i32x4*)(Bs + offB1[j]);
                bj[0] = lo[0]; bj[1] = lo[1]; bj[2] = lo[2]; bj[3] = lo[3];
                bj[4] = hi[0]; bj[5] = hi[1]; bj[6] = hi[2]; bj[7] = hi[3];
            }
#pragma unroll
            for (int i = 0; i < 4; i++)
                acc[i][j] = __builtin_amdgcn_mfma_scale_f32_16x16x128_f8f6f4(
                    af[i], bj, acc[i][j], 0, 0, 0, 127, 0, SCALE_B);
        }
        __syncthreads();
    }

    // epilogue: C/D layout col=lane&15, row=(lane>>4)*4+reg
#pragma unroll
    for (int j = 0; j < 4; j++) {
        const int n = bn0 + wn + j * 16 + lrow;
        const float bn_bias = (MODE == MODE_LRELU_FP8) ? bias[n] : 0.f;
#pragma unroll
        for (int i = 0; i < 4; i++) {
#pragma unroll
            for (int r = 0; r < 4; r++) {
                const int m = bm0 + wm + i * 16 + lq * 4 + r;
                const long off = (long)z * strideO + (long)m * N + n;
                float v = acc[i][j][r];
                if (MODE == MODE_LRELU_FP8) {
                    v += bn_bias;
                    v = v > 0.f ? v : 0.01f * v;
                    ((unsigned char*)Out)[off] = f2fp8(v);
                } else {
                    ((bf16*)Out)[off] = __float2bfloat16(v);
                }
            }
        }
    }
}

// ---------- fused dual GEMM, MX-fp8, wave-split f/g. BM=128, BN=64.
// waves 0-1: fuse matrix (rows wm=0/64); waves 2-3: gate matrix (same rows).
// Single-matrix 4x4 acc per wave (64 regs) -> ~135 live regs, safe at 3 blocks/CU.
__global__ __launch_bounds__(256, 3)
void gemm_dual_fp8(const unsigned char* __restrict__ A8,
                   const unsigned char* __restrict__ Bf8,
                   const unsigned char* __restrict__ Bg8,
                   float* __restrict__ Out,
                   const float* __restrict__ biasf, const float* __restrict__ biasg,
                   const unsigned char* __restrict__ cat8,
                   const int* __restrict__ cmask) {
    constexpr int BM = 128, BN = 64;
    constexpr int N = FEAT, K = FEAT;
    // single contiguous smem block: As[16K] | Bfs[8K] | Bgs[8K]; the whole 32 KB
    // is reused as the f->g handoff scratch in the epilogue.
    __shared__ __align__(16) char smem[32768];
    char* As = smem;
    char* Bfs = smem + 16384;
    char* Bgs = smem + 24576;

    const int tid = threadIdx.x;
    const int wave = tid >> 6, lane = tid & 63;
    const int isG = wave >> 1;           // 0 = fuse waves, 1 = gate waves
    const int wm = (wave & 1) * 64;
    const int lrow = lane & 15, lq = lane >> 4;

    const int bm0 = blockIdx.y * BM;
    const int bn0 = blockIdx.x * BN;

    const int p = tid & 7, r0 = tid >> 3;
    const int xo = (p ^ (r0 & 7)) * 16;
    const unsigned char* agp = A8 + (long)(bm0 + r0) * K + xo;
    const unsigned char* bfgp = Bf8 + (long)(bn0 + r0) * K + xo;
    const unsigned char* bggp = Bg8 + (long)(bn0 + r0) * K + xo;
    char* asl = As + tid * 16;
    char* bfl = Bfs + tid * 16;
    char* bgl = Bgs + tid * 16;
    const long rowskip = (long)32 * K;

    // fragment ds_read offsets. A rows wm+f*16+lrow; B rows j*16+lrow (all 64).
    const char* Bsrc = isG ? Bgs : Bfs;
    int offA0[4], offA1[4], offB0[4], offB1[4];
#pragma unroll
    for (int f = 0; f < 4; f++) {
        const int ra = wm + f * 16 + lrow;
        offA0[f] = ra * 128 + (((lq * 2 + 0) ^ (ra & 7)) * 16);
        offA1[f] = ra * 128 + (((lq * 2 + 1) ^ (ra & 7)) * 16);
        const int rb = f * 16 + lrow;
        offB0[f] = rb * 128 + (((lq * 2 + 0) ^ (rb & 7)) * 16);
        offB1[f] = rb * 128 + (((lq * 2 + 1) ^ (rb & 7)) * 16);
    }

    f32x4 acc[4][4];
#pragma unroll
    for (int i = 0; i < 4; i++)
#pragma unroll
        for (int j = 0; j < 4; j++) acc[i][j] = (f32x4){0.f, 0.f, 0.f, 0.f};

    for (int k0 = 0; k0 < K; k0 += 128) {
#pragma unroll
        for (int r = 0; r < 4; r++)
            GLL(agp + (long)r * rowskip, asl + r * 4096);
#pragma unroll
        for (int r = 0; r < 2; r++) {
            GLL(bfgp + (long)r * rowskip, bfl + r * 4096);
            GLL(bggp + (long)r * rowskip, bgl + r * 4096);
        }
        agp += 128; bfgp += 128; bggp += 128;
        __syncthreads();

        i32x8 af[4];
#pragma unroll
        for (int f = 0; f < 4; f++) {
            const i32x4 lo = *(const i32x4*)(As + offA0[f]);
            const i32x4 hi = *(const i32x4*)(As + offA1[f]);
            af[f][0] = lo[0]; af[f][1] = lo[1]; af[f][2] = lo[2]; af[f][3] = lo[3];
            af[f][4] = hi[0]; af[f][5] = hi[1]; af[f][6] = hi[2]; af[f][7] = hi[3];
        }
#pragma unroll
        for (int j = 0; j < 4; j++) {
            i32x8 bj;
            {
                const i32x4 lo = *(const i32x4*)(Bsrc + offB0[j]);
                const i32x4 hi = *(const i32x4*)(Bsrc + offB1[j]);
                bj[0] = lo[0]; bj[1] = lo[1]; bj[2] = lo[2]; bj[3] = lo[3];
                bj[4] = hi[0]; bj[5] = hi[1]; bj[6] = hi[2]; bj[7] = hi[3];
            }
#pragma unroll
            for (int i = 0; i < 4; i++)
                acc[i][j] = __builtin_amdgcn_mfma_scale_f32_16x16x128_f8f6f4(
                    af[i], bj, acc[i][j], 0, 0, 0, 127, 0, 122);
        }
        __syncthreads();
    }

    // ---- epilogue: f-waves tanh -> LDS scratch; barrier; g-waves blend+store ----
    float* scratch = (float*)smem;      // 2 slots x 4096 floats (16 KB each)
    const int slot = (wave & 1) * 4096;
    if (!isG) {
#pragma unroll
        for (int j = 0; j < 4; j++) {
            const float bfb = biasf[bn0 + j * 16 + lrow];
#pragma unroll
            for (int i = 0; i < 4; i++) {
#pragma unroll
                for (int r = 0; r < 4; r++) {
                    const float vf = acc[i][j][r] + bfb;
                    const float e = __expf(2.0f * fabsf(vf));
                    const float th = copysignf(1.0f - 2.0f / (e + 1.0f), vf);
                    scratch[slot + ((i * 4 + j) * 4 + r) * 64 + lane] = th;
                }
            }
        }
    }
    __syncthreads();
    if (isG) {
#pragma unroll
        for (int j = 0; j < 4; j++) {
            const int n = bn0 + j * 16 + lrow;
            const float bgb = biasg[n];
#pragma unroll
            for (int i = 0; i < 4; i++) {
#pragma unroll
                for (int r = 0; r < 4; r++) {
                    const int m = bm0 + wm + i * 16 + lq * 4 + r;
                    const long off = (long)m * N + n;
                    const float vg = acc[i][j][r] + bgb;
                    const float g = 1.0f / (1.0f + __expf(-vg));
                    const float th = scratch[slot + ((i * 4 + j) * 4 + r) * 64 + lane];
                    const float c = fp8_to_f(cat8[off]);
                    Out[off] = cmask[m] ? (g * th + (1.0f - g) * c) : NEG_INF_F;
                }
            }
        }
    }
}

// ---------- masked row softmax: S bf16 in, S_ fp8 out ----------
__global__ __launch_bounds__(256) void softmax_rows(const bf16* __restrict__ S,
                                                    unsigned char* __restrict__ S8,
                                                    const int* __restrict__ Cmask,
                                                    const int* __restrict__ Qmask) {
    const int row = blockIdx.x;         // 0 .. MC-1
    const int b = row >> 11;            // LC = 2048
    const int tid = threadIdx.x;
    const bf16* srow = S + (long)row * LQ;
    unsigned char* orow = S8 + (long)row * LQ;
    const int* qm = Qmask + b * LQ;
    __shared__ float red[8];

    if (Cmask[row] == 0) {
        // ref: uniform 1/512 = 2^-9 = e4m3 byte 0x01 exactly
        orow[tid] = 0x01; orow[tid + 256] = 0x01;
        return;
    }
    const int q0 = qm[tid], q1 = qm[tid + 256];
    float v0 = q0 ? __bfloat162float(srow[tid]) : -3e38f;
    float v1 = q1 ? __bfloat162float(srow[tid + 256]) : -3e38f;
    float mx = fmaxf(v0, v1);
#pragma unroll
    for (int o = 32; o > 0; o >>= 1) mx = fmaxf(mx, __shfl_down(mx, o, 64));
    const int wave = tid >> 6, lane = tid & 63;
    if (lane == 0) red[wave] = mx;
    __syncthreads();
    const float m4 = fmaxf(fmaxf(red[0], red[1]), fmaxf(red[2], red[3]));
    float e0 = q0 ? __expf(v0 - m4) : 0.f;
    float e1 = q1 ? __expf(v1 - m4) : 0.f;
    float s = e0 + e1;
#pragma unroll
    for (int o = 32; o > 0; o >>= 1) s += __shfl_down(s, o, 64);
    if (lane == 0) red[4 + wave] = s;
    __syncthreads();
    const float tot = red[4] + red[5] + red[6] + red[7];
    if (!(tot > 0.f)) {
        orow[tid] = 0x01; orow[tid + 256] = 0x01;
        return;
    }
    const float inv = 1.0f / tot;
    orow[tid] = f2fp8(e0 * inv);
    orow[tid + 256] = f2fp8(e1 * inv);
}

// ---------- build cat = [C | attn | attn-C | attn*C] fp8, from f32 C + bf16 attn ----------
__global__ __launch_bounds__(256) void build_cat(const float* __restrict__ C,
                                                 const bf16* __restrict__ attn,
                                                 unsigned char* __restrict__ cat8) {
    const long t = (long)blockIdx.x * 256 + threadIdx.x;
    const int m = (int)(t >> 6);
    const int c = (int)(t & 63) << 3;
    const float4 c0 = *(const float4*)(C + (long)m * DIM + c);
    const float4 c1 = *(const float4*)(C + (long)m * DIM + c + 4);
    const s16x8 av = *(const s16x8*)((const short*)attn + (long)m * DIM + c);
    float cf[8] = {c0.x, c0.y, c0.z, c0.w, c1.x, c1.y, c1.z, c1.w};
    float af_[8];
#pragma unroll
    for (int i = 0; i < 8; i++) af_[i] = bfs2f(av[i]);
    unsigned char* rowp = cat8 + (long)m * FEAT + c;
    *(uint2*)(rowp) = pk8fp8(cf[0], cf[1], cf[2], cf[3], cf[4], cf[5], cf[6], cf[7]);
    *(uint2*)(rowp + 512) = pk8fp8(af_[0], af_[1], af_[2], af_[3], af_[4], af_[5], af_[6], af_[7]);
    *(uint2*)(rowp + 1024) = pk8fp8(af_[0] - cf[0], af_[1] - cf[1], af_[2] - cf[2], af_[3] - cf[3],
                                    af_[4] - cf[4], af_[5] - cf[5], af_[6] - cf[6], af_[7] - cf[7]);
    *(uint2*)(rowp + 1536) = pk8fp8(af_[0] * cf[0], af_[1] * cf[1], af_[2] * cf[2], af_[3] * cf[3],
                                    af_[4] * cf[4], af_[5] * cf[5], af_[6] * cf[6], af_[7] * cf[7]);
}

extern "C" void kernel_launch(void* const* d_in, const int* in_sizes, int n_in,
                              void* d_out, int out_size, void* d_ws, size_t ws_size,
                              hipStream_t stream) {
    (void)in_sizes; (void)n_in; (void)out_size; (void)ws_size;
    const float* C = (const float*)d_in[0];
    const float* Q = (const float*)d_in[1];
    const int* Cmask = (const int*)d_in[2];
    const int* Qmask = (const int*)d_in[3];
    const float* W1 = (const float*)d_in[4];
    const float* b1 = (const float*)d_in[5];
    const float* Wf = (const float*)d_in[6];
    const float* bfp = (const float*)d_in[7];
    const float* Wg = (const float*)d_in[8];
    const float* bgp = (const float*)d_in[9];
    float* out = (float*)d_out;

    // ---- workspace layout. Everything below 134,217,728 is dead before
    // build_cat writes cat8 (first 67 MB); attn/Wf8/Wg8 live above. ----
    char* ws = (char*)d_ws;
    unsigned char* cat8 = (unsigned char*)(ws + 0);          //  67,108,864
    unsigned char* C8   = (unsigned char*)(ws + 0);          //  16,777,216 (dead after lrelu-C)
    unsigned char* Q8   = (unsigned char*)(ws + 16777216);   //   4,194,304 (dead after lrelu-Q)
    unsigned char* Qt8  = (unsigned char*)(ws + 20971520);   //   4,194,304 (dead after attn)
    unsigned char* C_8  = (unsigned char*)(ws + 25165824);   //  16,777,216 (dead after S)
    unsigned char* Q_8  = (unsigned char*)(ws + 41943040);   //   4,194,304 (dead after S)
    bf16*          S    = (bf16*)(ws + 46137344);            //  33,554,432 (dead after softmax)
    unsigned char* S_8  = (unsigned char*)(ws + 79691776);   //  16,777,216 (dead after attn)
    unsigned char* W1_8 = (unsigned char*)(ws + 96468992);   //     262,144
    bf16*          attn = (bf16*)(ws + 134217728);           //  33,554,432
    unsigned char* Wf8  = (unsigned char*)(ws + 167772160);  //   4,194,304
    unsigned char* Wg8  = (unsigned char*)(ws + 171966464);  //   4,194,304 (end ~176 MB)

    // 1. conversions: activations scale 1, weights pre-scaled x32 (MX scale 2^-5)
    cvt_f32_fp8<<<16384, 256, 0, stream>>>(C, C8, MC * DIM, 1.0f);
    cvt_f32_fp8<<<4096, 256, 0, stream>>>(Q, Q8, MQ * DIM, 1.0f);
    cvt_f32_fp8<<<256, 256, 0, stream>>>(W1, W1_8, DIM * DIM, 32.0f);
    cvt_f32_fp8<<<4096, 256, 0, stream>>>(Wf, Wf8, FEAT * FEAT, 32.0f);
    cvt_f32_fp8<<<4096, 256, 0, stream>>>(Wg, Wg8, FEAT * FEAT, 32.0f);
    transpose_q_fp8<<<dim3(16, 16, 16), dim3(32, 8), 0, stream>>>(Q, Qt8);

    // 2. C_ = lrelu(C@W1^T + b1) fp8 ; Q_ likewise (B-scale 2^-5 = byte 122)
    gemm_fp8<MODE_LRELU_FP8, 122><<<dim3(4, 256, 1), 256, 0, stream>>>(
        C8, W1_8, C_8, b1, DIM, DIM, 0, 0, 0);
    gemm_fp8<MODE_LRELU_FP8, 122><<<dim3(4, 64, 1), 256, 0, stream>>>(
        Q8, W1_8, Q_8, b1, DIM, DIM, 0, 0, 0);

    // 3. S[b] = C_[b] @ Q_[b]^T  (bf16 logits; both operands scale 1 = byte 127)
    gemm_fp8<MODE_BF16, 127><<<dim3(4, 16, 16), 256, 0, stream>>>(
        C_8, Q_8, S, nullptr, LQ, DIM,
        (long)LC * DIM, (long)LQ * DIM, (long)LC * LQ);

    // 4. masked softmax -> S_ fp8
    softmax_rows<<<MC, 256, 0, stream>>>(S, S_8, Cmask, Qmask);

    // 5. attn[b] = S_[b] @ Q[b]  (B = Qt8)  -> bf16
    gemm_fp8<MODE_BF16, 127><<<dim3(4, 16, 16), 256, 0, stream>>>(
        S_8, Qt8, attn, nullptr, DIM, LQ,
        (long)LC * LQ, (long)DIM * LQ, (long)LC * DIM);

    // 6. cat8 = [C | attn | attn-C | attn*C] (fp8, from f32 C)
    build_cat<<<8192, 256, 0, stream>>>(C, attn, cat8);

    // 7+8 fused dual MX-fp8 GEMM (wave-split f/g) + activations + blend + Cmask
    gemm_dual_fp8<<<dim3(32, 256, 1), 256, 0, stream>>>(
        cat8, Wf8, Wg8, out, bfp, bgp, cat8, Cmask);
}